// Round 3
// baseline (2829.774 us; speedup 1.0000x reference)
//
#include <hip/hip_runtime.h>
#include <hip/hip_bf16.h>
#include <stdint.h>
#include <stddef.h>

// tidigitsRNNPT: Elman RNN (B=128, SEQ=254, FEAT=39, HID=1024) -> FC1(260096->100)+ReLU -> FC2(100->10) -> log_softmax
//
// R2: barrier-free dataflow scan. R1 post-mortem: 5.5us/step = ~4 serialized IF
// round trips (store drain, flag store, poll, h load). Now consumers poll the h
// DATA itself: hs slices are pre-poisoned 0xAA and bf16 0xAAAA (-3.02e-13) is
// unproducible by f2bf(fast_tanh(.)) (output is exactly 0 below ~1e-7) and by
// h0 (uniform [0,1), sign=0). Dword-granular validity (producer dword stores
// are atomic). No flags, no syncthreads, no store drain -> ~1.5 round trips/step.
// MFMA operands swapped (A<->B, layouts transpose-symmetric) so lane output =
// 4 consecutive h at one b -> single 8B packed store / 8B xp load.

typedef unsigned short u16;
typedef unsigned int u32;
typedef __attribute__((ext_vector_type(2))) unsigned int u32x2;
typedef __attribute__((ext_vector_type(4))) float f32x4;
typedef __attribute__((ext_vector_type(4))) unsigned short u16x4;
typedef __attribute__((ext_vector_type(8))) short short8;

#define SEQ   254
#define BATCH 128
#define HID   1024
#define FEAT  39
#define FC1N  100
#define FC1P  112
#define NCLS  10
#define NBLK_SCAN 128
#define SENT  0xAAAAAAAAu

// ---- workspace layout ----
#define OFF_HS    ((size_t)0)                                      // (SEQ+1)*128*1024 bf16 = 66.8MB
#define OFF_WHH   (OFF_HS + (size_t)(SEQ + 1) * BATCH * HID * 2)   // 2MB
#define OFF_XP    (OFF_WHH + (size_t)HID * HID * 2)                // 66.6MB
#define OFF_PART  (OFF_XP + (size_t)SEQ * BATCH * HID * 2)         // 14.6MB

__device__ inline u16 f2bf(float f){
  union { float f; unsigned u; } v; v.f = f;
  unsigned u = v.u;
  u += 0x7fffu + ((u >> 16) & 1u);
  return (u16)(u >> 16);
}
__device__ inline float bf2f(u16 h){
  union { unsigned u; float f; } v; v.u = ((unsigned)h) << 16;
  return v.f;
}
__device__ inline float fast_tanh(float x){
  float e = __expf(2.0f * x);
  return 1.0f - 2.0f / (e + 1.0f);
}

// ---- IF-coherent (cross-XCD) ops ----
__device__ inline short8 ld_cohx4(const u16* p){
  short8 r;
  asm volatile("global_load_dwordx4 %0, %1, off sc0 sc1" : "=v"(r) : "v"(p) : "memory");
  return r;
}
__device__ inline void st_cohx2(u16* p, u32x2 v){
  asm volatile("global_store_dwordx2 %0, %1, off sc0 sc1" :: "v"(p), "v"(v) : "memory");
}

__device__ inline bool frag_bad(short8 v){
  union { short8 s; u32 w[4]; } u; u.s = v;
  return (u.w[0] == SENT) | (u.w[1] == SENT) | (u.w[2] == SENT) | (u.w[3] == SENT);
}
__device__ inline unsigned wave_or32(unsigned v){
  #pragma unroll
  for (int i = 1; i < 64; i <<= 1) v |= __shfl_xor(v, i, 64);
  return __builtin_amdgcn_readfirstlane(v);
}

// ---------------- fp32 -> bf16 bulk convert ----------------
__global__ void cvt_f32_bf16_kernel(const float* __restrict__ in, u16* __restrict__ out, int n4){
  int i = blockIdx.x * blockDim.x + threadIdx.x;
  if (i < n4){
    f32x4 v = *(const f32x4*)(in + (size_t)i * 4);
    u16x4 o;
    o[0] = f2bf(v[0]); o[1] = f2bf(v[1]); o[2] = f2bf(v[2]); o[3] = f2bf(v[3]);
    *(u16x4*)(out + (size_t)i * 4) = o;
  }
}

// ---------------- xproj: [SEQ][BATCH][HID] bf16 (includes both biases) ----------------
__global__ __launch_bounds__(1024) void xproj_kernel(const float* __restrict__ x,
                                                     const float* __restrict__ W_ih,
                                                     const float* __restrict__ b_ih,
                                                     const float* __restrict__ b_hh,
                                                     u16* __restrict__ xp){
  const int s = blockIdx.x;
  __shared__ float xs[BATCH * (FEAT + 1)];
  for (int i = threadIdx.x; i < BATCH * FEAT; i += 1024){
    int b = i / FEAT, f = i - b * FEAT;
    xs[b * (FEAT + 1) + f] = x[((size_t)b * SEQ + s) * FEAT + f];
  }
  __syncthreads();
  const int h = threadIdx.x;
  float w[FEAT];
  #pragma unroll
  for (int f = 0; f < FEAT; ++f) w[f] = W_ih[h * FEAT + f];
  const float bias = b_ih[h] + b_hh[h];
  for (int b = 0; b < BATCH; ++b){
    float acc = bias;
    #pragma unroll
    for (int f = 0; f < FEAT; ++f) acc += xs[b * (FEAT + 1) + f] * w[f];
    xp[((size_t)s * BATCH + b) * HID + h] = f2bf(acc);
  }
}

// ---------------- barrier-free dataflow RNN scan ----------------
// 128 blocks, 1/CU co-resident (VGPR-heavy). Block (bgrp=bid&7, hgrp=bid>>3)
// computes h[16 b][64 h]. Step s: poll-load full h_s[16b][1024] (retry while any
// dword == SENT), MFMA (D[h][b] via swapped operands), tanh, pack, 8B store into
// write-once slice s+1. No flags, no barriers, no drains.
__global__ __launch_bounds__(256, 1) void scan_kernel(const u16* __restrict__ whh,
                                                      const u16* __restrict__ xp,
                                                      u16* __restrict__ hs){
  const int bid  = blockIdx.x;
  const int bgrp = bid & 7;
  const int hgrp = bid >> 3;
  const int wid  = threadIdx.x >> 6;
  const int lane = threadIdx.x & 63;
  const int lr = lane & 15;
  const int lg = lane >> 4;
  const int b_base = bgrp * 16;
  const int h_base = hgrp * 64 + wid * 16;

  // W_hh slice (A-operand): breg[kk] = W[h_base+lr][kk*32 + lg*8 .. +7]
  short8 breg[32];
  {
    const u16* wp = whh + (size_t)(h_base + lr) * HID + lg * 8;
    #pragma unroll
    for (int kk = 0; kk < 32; ++kk) breg[kk] = *(const short8*)(wp + kk * 32);
  }

  const int arow = (b_base + lr) * HID + lg * 8;   // B-operand: h[b=lr][k]
  const int b_o  = b_base + lr;                     // C/D col
  const int h_o  = h_base + lg * 4;                 // C/D rows (4 consecutive h)

  for (int s = 0; s < SEQ; ++s){
    const u16* pa = hs + (size_t)s * (BATCH * HID) + arow;

    // batch-issue all 32 h-fragment loads, one wait
    short8 a[32];
    #pragma unroll
    for (int kk = 0; kk < 32; ++kk) a[kk] = ld_cohx4(pa + kk * 32);
    asm volatile("s_waitcnt vmcnt(0)" ::: "memory");
    __builtin_amdgcn_sched_barrier(0);

    // validity: retry fragments containing sentinel dwords
    unsigned bad = 0;
    #pragma unroll
    for (int kk = 0; kk < 32; ++kk) bad |= frag_bad(a[kk]) ? (1u << kk) : 0u;
    bad = wave_or32(bad);
    while (bad){
      #pragma unroll
      for (int kk = 0; kk < 32; ++kk)
        if (bad & (1u << kk)) a[kk] = ld_cohx4(pa + kk * 32);
      asm volatile("s_waitcnt vmcnt(0)" ::: "memory");
      __builtin_amdgcn_sched_barrier(0);
      unsigned nb = 0;
      #pragma unroll
      for (int kk = 0; kk < 32; ++kk)
        if (bad & (1u << kk)) nb |= frag_bad(a[kk]) ? (1u << kk) : 0u;
      bad = wave_or32(nb);
    }
    __builtin_amdgcn_sched_barrier(0);

    // acc init from xproj: 4 consecutive h at one b -> one 8B load
    u16x4 xv = *(const u16x4*)(xp + ((size_t)s * BATCH + b_o) * HID + h_o);
    f32x4 acc;
    acc[0] = bf2f(xv[0]); acc[1] = bf2f(xv[1]); acc[2] = bf2f(xv[2]); acc[3] = bf2f(xv[3]);

    #pragma unroll
    for (int kk = 0; kk < 32; ++kk)
      acc = __builtin_amdgcn_mfma_f32_16x16x32_bf16(breg[kk], a[kk], acc, 0, 0, 0);

    // tanh -> pack 4 bf16 -> one 8B store into slice s+1
    u32x2 d;
    d[0] = (u32)f2bf(fast_tanh(acc[0])) | ((u32)f2bf(fast_tanh(acc[1])) << 16);
    d[1] = (u32)f2bf(fast_tanh(acc[2])) | ((u32)f2bf(fast_tanh(acc[3])) << 16);
    st_cohx2(hs + (size_t)(s + 1) * (BATCH * HID) + (size_t)b_o * HID + h_o, d);
  }
}

// ---------------- FC1 partials via MFMA ----------------
__global__ __launch_bounds__(256) void fc1_kernel(const u16* __restrict__ outs,
                                                  const float* __restrict__ W1,
                                                  float* __restrict__ part){
  const int s = blockIdx.x;
  const int wid  = threadIdx.x >> 6;
  const int lane = threadIdx.x & 63;
  const int lr = lane & 15;
  const int lg = lane >> 4;

  f32x4 acc[2][7];
  const f32x4 zero = {0.f, 0.f, 0.f, 0.f};
  #pragma unroll
  for (int i = 0; i < 2; ++i)
    #pragma unroll
    for (int n = 0; n < 7; ++n) acc[i][n] = zero;

  const u16* pa0 = outs + ((size_t)s * BATCH + wid * 32 + lr) * HID + lg * 8;
  const u16* pa1 = pa0 + 16 * HID;

  for (int kk = 0; kk < 32; ++kk){
    short8 a0 = *(const short8*)(pa0 + kk * 32);
    short8 a1 = *(const short8*)(pa1 + kk * 32);
    #pragma unroll
    for (int nt = 0; nt < 7; ++nt){
      const int j = nt * 16 + lr;
      short8 bf;
      if (j < FC1N){
        const float* wp = W1 + (size_t)j * (SEQ * HID) + (size_t)s * HID + kk * 32 + lg * 8;
        f32x4 w0 = *(const f32x4*)wp;
        f32x4 w1 = *(const f32x4*)(wp + 4);
        #pragma unroll
        for (int r = 0; r < 4; ++r){ bf[r] = (short)f2bf(w0[r]); bf[r + 4] = (short)f2bf(w1[r]); }
      } else {
        #pragma unroll
        for (int r = 0; r < 8; ++r) bf[r] = 0;
      }
      acc[0][nt] = __builtin_amdgcn_mfma_f32_16x16x32_bf16(a0, bf, acc[0][nt], 0, 0, 0);
      acc[1][nt] = __builtin_amdgcn_mfma_f32_16x16x32_bf16(a1, bf, acc[1][nt], 0, 0, 0);
    }
  }

  #pragma unroll
  for (int i = 0; i < 2; ++i)
    #pragma unroll
    for (int nt = 0; nt < 7; ++nt)
      #pragma unroll
      for (int r = 0; r < 4; ++r){
        const int b = wid * 32 + i * 16 + lg * 4 + r;
        const int j = nt * 16 + lr;
        part[((size_t)s * BATCH + b) * FC1P + j] = acc[i][nt][r];
      }
}

// ---------------- reduce partials + bias + relu + FC2 + log_softmax ----------------
__global__ __launch_bounds__(128) void reduce_kernel(const float* __restrict__ part,
                                                     const float* __restrict__ b1,
                                                     const float* __restrict__ W2,
                                                     const float* __restrict__ b2,
                                                     float* __restrict__ out){
  const int b = blockIdx.x;
  const int j = threadIdx.x;
  __shared__ float h1[FC1N];
  __shared__ float lgt[NCLS];

  if (j < FC1P){
    const float* p = part + (size_t)b * FC1P + j;
    float acc = 0.f;
    #pragma unroll 4
    for (int s = 0; s < SEQ; ++s) acc += p[(size_t)s * BATCH * FC1P];
    if (j < FC1N) h1[j] = fmaxf(acc + b1[j], 0.f);
  }
  __syncthreads();
  if (j < NCLS){
    float v = b2[j];
    for (int q = 0; q < FC1N; ++q) v += h1[q] * W2[j * FC1N + q];
    lgt[j] = v;
  }
  __syncthreads();
  if (j < NCLS){
    float m = lgt[0];
    #pragma unroll
    for (int q = 1; q < NCLS; ++q) m = fmaxf(m, lgt[q]);
    float sum = 0.f;
    #pragma unroll
    for (int q = 0; q < NCLS; ++q) sum += __expf(lgt[q] - m);
    out[b * NCLS + j] = lgt[j] - (m + __logf(sum));
  }
}

extern "C" void kernel_launch(void* const* d_in, const int* in_sizes, int n_in,
                              void* d_out, int out_size, void* d_ws, size_t ws_size,
                              hipStream_t stream){
  (void)in_sizes; (void)n_in; (void)out_size; (void)ws_size;
  const float* x   = (const float*)d_in[0];
  const float* h0  = (const float*)d_in[1];
  const float* Wih = (const float*)d_in[2];
  const float* Whh = (const float*)d_in[3];
  const float* bih = (const float*)d_in[4];
  const float* bhh = (const float*)d_in[5];
  const float* W1  = (const float*)d_in[6];
  const float* b1  = (const float*)d_in[7];
  const float* W2  = (const float*)d_in[8];
  const float* b2  = (const float*)d_in[9];
  float* out = (float*)d_out;

  char* ws = (char*)d_ws;
  u16*  hs    = (u16*)(ws + OFF_HS);
  u16*  whh   = (u16*)(ws + OFF_WHH);
  u16*  xp    = (u16*)(ws + OFF_XP);
  float* part = (float*)(ws + OFF_PART);

  // sentinel-fill h slices 1..SEQ (slice 0 overwritten by cvt(h0))
  hipMemsetAsync(hs + (size_t)BATCH * HID, 0xAA, (size_t)SEQ * BATCH * HID * 2, stream);
  cvt_f32_bf16_kernel<<<1024, 256, 0, stream>>>(Whh, whh, (HID * HID) / 4);
  cvt_f32_bf16_kernel<<<128, 256, 0, stream>>>(h0, hs, (BATCH * HID) / 4);
  xproj_kernel<<<SEQ, 1024, 0, stream>>>(x, Wih, bih, bhh, xp);
  scan_kernel<<<NBLK_SCAN, 256, 0, stream>>>(whh, xp, hs);
  fc1_kernel<<<SEQ, 256, 0, stream>>>(hs + (size_t)BATCH * HID, W1, part);
  reduce_kernel<<<BATCH, 128, 0, stream>>>(part, b1, W2, b2, out);
}